// Round 1
// baseline (662.365 us; speedup 1.0000x reference)
//
#include <hip/hip_runtime.h>

#define N_NODES 25000
#define N_EDGES 400000

// ---------------- fast transcendentals (fp32, ~2ulp) ----------------
__device__ __forceinline__ float fast_sigmoid(float x) {
    return __builtin_amdgcn_rcpf(1.0f + __expf(-x));
}
__device__ __forceinline__ float fast_tanh(float x) {
    return 1.0f - 2.0f * __builtin_amdgcn_rcpf(__expf(2.0f * x) + 1.0f);
}

// Q[n, f, m] = sum_h W_edge[f, m*16+h] * h[h]   (f = lane's j slice)
// Qb[n, m=j] = sum_h b_edge[m*16+h] * h[h]
// Qrow layout: 272 floats per node: f*16+m for f in 0..15, then [256+m] = Qb
__device__ __forceinline__ void compute_q_lane(const float* h, int j,
        const float* __restrict__ We, const float* __restrict__ be,
        float* __restrict__ Qrow)
{
    const float4* w4 = (const float4*)(We + j * 256);
    float q[16];
#pragma unroll
    for (int m = 0; m < 16; ++m) {
        float4 wa = w4[m*4+0], wb = w4[m*4+1], wc = w4[m*4+2], wd = w4[m*4+3];
        float acc;
        acc  = wa.x*h[0]  + wa.y*h[1]  + wa.z*h[2]  + wa.w*h[3];
        acc += wb.x*h[4]  + wb.y*h[5]  + wb.z*h[6]  + wb.w*h[7];
        acc += wc.x*h[8]  + wc.y*h[9]  + wc.z*h[10] + wc.w*h[11];
        acc += wd.x*h[12] + wd.y*h[13] + wd.z*h[14] + wd.w*h[15];
        q[m] = acc;
    }
    float4* qs = (float4*)(Qrow + j * 16);
    qs[0] = make_float4(q[0],  q[1],  q[2],  q[3]);
    qs[1] = make_float4(q[4],  q[5],  q[6],  q[7]);
    qs[2] = make_float4(q[8],  q[9],  q[10], q[11]);
    qs[3] = make_float4(q[12], q[13], q[14], q[15]);
    const float4* b4 = (const float4*)(be + j * 16);
    float4 ba = b4[0], bb = b4[1], bc = b4[2], bd = b4[3];
    float accb;
    accb  = ba.x*h[0]  + ba.y*h[1]  + ba.z*h[2]  + ba.w*h[3];
    accb += bb.x*h[4]  + bb.y*h[5]  + bb.z*h[6]  + bb.w*h[7];
    accb += bc.x*h[8]  + bc.y*h[9]  + bc.z*h[10] + bc.w*h[11];
    accb += bd.x*h[12] + bd.y*h[13] + bd.z*h[14] + bd.w*h[15];
    Qrow[256 + j] = accb;
}

// ---------------- K1: hidden0 = nf @ W_init + b_init ; copy; Q(h0); zero cnt --------
__global__ void __launch_bounds__(256) k_init(
        const float* __restrict__ nf, const float* __restrict__ Wini,
        const float* __restrict__ bini,
        const float* __restrict__ We, const float* __restrict__ be,
        float* __restrict__ hidden0, float* __restrict__ hid,
        float* __restrict__ Q, int* __restrict__ cnt)
{
    int gtid = blockIdx.x * 256 + threadIdx.x;
    if (gtid <= N_NODES) cnt[gtid] = 0;
    int node = gtid >> 4;
    int j = gtid & 15;
    if (node >= N_NODES) return;

    const float4* nf4 = (const float4*)(nf + node * 32);
    float acc = bini[j];
#pragma unroll
    for (int g = 0; g < 8; ++g) {
        float4 v = nf4[g];
        acc = fmaf(v.x, Wini[(g*4+0)*16 + j], acc);
        acc = fmaf(v.y, Wini[(g*4+1)*16 + j], acc);
        acc = fmaf(v.z, Wini[(g*4+2)*16 + j], acc);
        acc = fmaf(v.w, Wini[(g*4+3)*16 + j], acc);
    }
    hidden0[node*16 + j] = acc;
    hid[node*16 + j] = acc;

    float h[16];
#pragma unroll
    for (int l = 0; l < 16; ++l) h[l] = __shfl(acc, l, 16);
    compute_q_lane(h, j, We, be, Q + (size_t)node * 272);
}

// ---------------- CSR build ----------------
__global__ void __launch_bounds__(256) k_hist(const int* __restrict__ recv,
                                              int* __restrict__ cnt)
{
    int e = blockIdx.x * 256 + threadIdx.x;
    if (e < N_EDGES) atomicAdd(&cnt[recv[e]], 1);
}

__global__ void __launch_bounds__(1024) k_scan(const int* __restrict__ cnt,
        int* __restrict__ row_ptr, int* __restrict__ cursor,
        float* __restrict__ out)
{
    __shared__ int sums[1024];
    int t = threadIdx.x;
    const int CH = (N_NODES + 1023) / 1024 + 1;   // 25 -> covers 25600
    int base = t * CH;
    int s = 0;
    for (int i = 0; i < CH; ++i) {
        int idx = base + i;
        if (idx < N_NODES) s += cnt[idx];
    }
    sums[t] = s;
    __syncthreads();
    // Hillis-Steele inclusive scan
    for (int off = 1; off < 1024; off <<= 1) {
        int add = (t >= off) ? sums[t - off] : 0;
        __syncthreads();
        sums[t] += add;
        __syncthreads();
    }
    int run = sums[t] - s;   // exclusive prefix of this chunk
    for (int i = 0; i < CH; ++i) {
        int idx = base + i;
        if (idx < N_NODES) {
            row_ptr[idx] = run;
            cursor[idx]  = run;
            run += cnt[idx];
        }
    }
    if (t == 0) { row_ptr[N_NODES] = N_EDGES; out[0] = 0.0f; }
}

__global__ void __launch_bounds__(256) k_scatter(const int* __restrict__ recv,
        int* __restrict__ cursor, int* __restrict__ eids)
{
    int e = blockIdx.x * 256 + threadIdx.x;
    if (e < N_EDGES) {
        int r = recv[e];
        int pos = atomicAdd(&cursor[r], 1);
        eids[pos] = e;
    }
}

// ---------------- K3: messages[n,m] = sum_{e->n} (Qb[s,m] + sum_f ef[e,f] Q[s,f,m]) ----
__global__ void __launch_bounds__(256) k_agg(
        const float* __restrict__ Q, const float* __restrict__ ef,
        const int* __restrict__ row_ptr, const int* __restrict__ eids,
        const int* __restrict__ senders, float* __restrict__ msgs)
{
    int gtid = blockIdx.x * 256 + threadIdx.x;
    int node = gtid >> 4;
    int m = gtid & 15;
    if (node >= N_NODES) return;
    int beg = row_ptr[node];
    int end = row_ptr[node + 1];
    float acc = 0.0f;
    for (int i = beg; i < end; ++i) {
        int eid = eids[i];
        int s = senders[eid];
        const float* qr = Q + (size_t)s * 272 + m;
        const float4* e4 = (const float4*)(ef + (size_t)eid * 16);
        float4 e0 = e4[0], e1 = e4[1], e2 = e4[2], e3 = e4[3];
        float a = qr[256];
        a = fmaf(e0.x, qr[0],   a);
        a = fmaf(e0.y, qr[16],  a);
        a = fmaf(e0.z, qr[32],  a);
        a = fmaf(e0.w, qr[48],  a);
        a = fmaf(e1.x, qr[64],  a);
        a = fmaf(e1.y, qr[80],  a);
        a = fmaf(e1.z, qr[96],  a);
        a = fmaf(e1.w, qr[112], a);
        a = fmaf(e2.x, qr[128], a);
        a = fmaf(e2.y, qr[144], a);
        a = fmaf(e2.z, qr[160], a);
        a = fmaf(e2.w, qr[176], a);
        a = fmaf(e3.x, qr[192], a);
        a = fmaf(e3.y, qr[208], a);
        a = fmaf(e3.z, qr[224], a);
        a = fmaf(e3.w, qr[240], a);
        acc += a;
    }
    msgs[node*16 + m] = acc;
}

// ---------------- K4: GRU over seq=[hid||msgs] (T=32), then Q(new hidden) ----------
// 16 lanes per node, lane j = GRU unit j. h replicated via wave-internal LDS.
__global__ void __launch_bounds__(256) k_gru(
        const float* __restrict__ hid_in, const float* __restrict__ msgs,
        const float* __restrict__ Wi, const float* __restrict__ Wh,
        const float* __restrict__ bi, const float* __restrict__ bh,
        const float* __restrict__ We, const float* __restrict__ be,
        float* __restrict__ hid_out, float* __restrict__ Q, int qflag)
{
    __shared__ float sh[256];
    int gtid = blockIdx.x * 256 + threadIdx.x;
    int node = gtid >> 4;
    int j = gtid & 15;
    if (node >= N_NODES) return;
    int lbase = (threadIdx.x >> 4) << 4;

    float Whz[16], Whr[16], Whh[16];
#pragma unroll
    for (int l = 0; l < 16; ++l) {
        Whz[l] = Wh[l*48 + j];
        Whr[l] = Wh[l*48 + 16 + j];
        Whh[l] = Wh[l*48 + 32 + j];
    }
    float Wiz = Wi[j], Wir = Wi[16+j], Wih = Wi[32+j];
    float cz = bi[j] + bh[j];            // z-gate biases merge
    float cr = bi[16+j] + bh[16+j];      // r-gate biases merge
    float bih_ = bi[32+j];               // h-gate: bh stays inside r*(...)
    float bhh_ = bh[32+j];

    float x[32];
    {
        const float4* a4 = (const float4*)(hid_in + node * 16);
        const float4* b4 = (const float4*)(msgs + node * 16);
#pragma unroll
        for (int g = 0; g < 4; ++g) {
            float4 v = a4[g];
            x[g*4+0]=v.x; x[g*4+1]=v.y; x[g*4+2]=v.z; x[g*4+3]=v.w;
        }
#pragma unroll
        for (int g = 0; g < 4; ++g) {
            float4 v = b4[g];
            x[16+g*4+0]=v.x; x[16+g*4+1]=v.y; x[16+g*4+2]=v.z; x[16+g*4+3]=v.w;
        }
    }

    float h[16];
#pragma unroll
    for (int l = 0; l < 16; ++l) h[l] = 0.0f;
    float hown = 0.0f;

#pragma unroll
    for (int t = 0; t < 32; ++t) {
        float xv = x[t];
        float hz = 0.0f, hr = 0.0f, hhs = 0.0f;
#pragma unroll
        for (int l = 0; l < 16; ++l) {
            hz  = fmaf(h[l], Whz[l], hz);
            hr  = fmaf(h[l], Whr[l], hr);
            hhs = fmaf(h[l], Whh[l], hhs);
        }
        float z  = fast_sigmoid(fmaf(xv, Wiz, cz) + hz);
        float r  = fast_sigmoid(fmaf(xv, Wir, cr) + hr);
        float hc = fast_tanh(fmaf(xv, Wih, bih_) + r * (hhs + bhh_));
        float hn = z * hown + (1.0f - z) * hc;
        hown = hn;
        sh[lbase + j] = hn;
        __builtin_amdgcn_wave_barrier();
        const float4* hp = (const float4*)(sh + lbase);
        float4 p0 = hp[0], p1 = hp[1], p2 = hp[2], p3 = hp[3];
        __builtin_amdgcn_wave_barrier();
        h[0]=p0.x;  h[1]=p0.y;  h[2]=p0.z;  h[3]=p0.w;
        h[4]=p1.x;  h[5]=p1.y;  h[6]=p1.z;  h[7]=p1.w;
        h[8]=p2.x;  h[9]=p2.y;  h[10]=p2.z; h[11]=p2.w;
        h[12]=p3.x; h[13]=p3.y; h[14]=p3.z; h[15]=p3.w;
    }
    hid_out[node*16 + j] = hown;
    if (qflag) {
        compute_q_lane(h, j, We, be, Q + (size_t)node * 272);
    }
}

// ---------------- K5: out = sum_n (concat(h,h0)@W_ri + b_ri) * (h@W_rj + b_rj) --------
__global__ void __launch_bounds__(256) k_readout(
        const float* __restrict__ hid, const float* __restrict__ hid0,
        const float* __restrict__ Wri, const float* __restrict__ bri,
        const float* __restrict__ Wrj, const float* __restrict__ brj,
        float* __restrict__ out)
{
    int n = blockIdx.x * 256 + threadIdx.x;
    float val = 0.0f;
    if (n < N_NODES) {
        const float4* h4 = (const float4*)(hid + n * 16);
        const float4* g4 = (const float4*)(hid0 + n * 16);
        float iv = bri[0];
        float jv = brj[0];
#pragma unroll
        for (int g = 0; g < 4; ++g) {
            float4 h  = h4[g];
            float4 h0 = g4[g];
            iv = fmaf(h.x,  Wri[g*4+0], iv);  iv = fmaf(h.y,  Wri[g*4+1], iv);
            iv = fmaf(h.z,  Wri[g*4+2], iv);  iv = fmaf(h.w,  Wri[g*4+3], iv);
            iv = fmaf(h0.x, Wri[16+g*4+0], iv); iv = fmaf(h0.y, Wri[16+g*4+1], iv);
            iv = fmaf(h0.z, Wri[16+g*4+2], iv); iv = fmaf(h0.w, Wri[16+g*4+3], iv);
            jv = fmaf(h.x,  Wrj[g*4+0], jv);  jv = fmaf(h.y,  Wrj[g*4+1], jv);
            jv = fmaf(h.z,  Wrj[g*4+2], jv);  jv = fmaf(h.w,  Wrj[g*4+3], jv);
        }
        val = iv * jv;
    }
#pragma unroll
    for (int off = 32; off > 0; off >>= 1)
        val += __shfl_xor(val, off, 64);
    __shared__ float wsum[4];
    int w = threadIdx.x >> 6;
    if ((threadIdx.x & 63) == 0) wsum[w] = val;
    __syncthreads();
    if (threadIdx.x == 0)
        atomicAdd(out, wsum[0] + wsum[1] + wsum[2] + wsum[3]);
}

// ---------------- launch ----------------
extern "C" void kernel_launch(void* const* d_in, const int* in_sizes, int n_in,
                              void* d_out, int out_size, void* d_ws, size_t ws_size,
                              hipStream_t stream)
{
    const float* node_features = (const float*)d_in[0];
    const float* edge_features = (const float*)d_in[1];
    const float* W_init = (const float*)d_in[2];
    const float* b_init = (const float*)d_in[3];
    const float* W_edge = (const float*)d_in[4];
    const float* b_edge = (const float*)d_in[5];
    const float* Wi_gru = (const float*)d_in[6];
    const float* Wh_gru = (const float*)d_in[7];
    const float* bi_gru = (const float*)d_in[8];
    const float* bh_gru = (const float*)d_in[9];
    const float* W_ri = (const float*)d_in[10];
    const float* b_ri = (const float*)d_in[11];
    const float* W_rj = (const float*)d_in[12];
    const float* b_rj = (const float*)d_in[13];
    const int* receivers = (const int*)d_in[14];
    const int* senders   = (const int*)d_in[15];
    float* out = (float*)d_out;

    // workspace carve (floats then ints); total ~35.5 MB
    float* fb      = (float*)d_ws;
    float* hidden0 = fb;                 // 400000
    float* hidA    = fb + 400000;        // 400000
    float* hidB    = fb + 800000;        // 400000
    float* msgs    = fb + 1200000;       // 400000
    float* Q       = fb + 1600000;       // 25000*272 = 6.8M
    int* ib      = (int*)(fb + 8400000);
    int* cnt     = ib;                   // 25024
    int* row_ptr = ib + 25024;           // 25024
    int* cursor  = ib + 50048;           // 25024
    int* eids    = ib + 75072;           // 400000

    dim3 b256(256);
    int grid_n16 = (N_NODES * 16 + 255) / 256;   // 1563
    int grid_e   = (N_EDGES + 255) / 256;        // 1563
    int grid_n   = (N_NODES + 255) / 256;        // 98

    k_init<<<grid_n16, b256, 0, stream>>>(node_features, W_init, b_init,
                                          W_edge, b_edge, hidden0, hidA, Q, cnt);
    k_hist<<<grid_e, b256, 0, stream>>>(receivers, cnt);
    k_scan<<<1, 1024, 0, stream>>>(cnt, row_ptr, cursor, out);
    k_scatter<<<grid_e, b256, 0, stream>>>(receivers, cursor, eids);

    // iteration 1: hidA -> hidB
    k_agg<<<grid_n16, b256, 0, stream>>>(Q, edge_features, row_ptr, eids, senders, msgs);
    k_gru<<<grid_n16, b256, 0, stream>>>(hidA, msgs, Wi_gru, Wh_gru, bi_gru, bh_gru,
                                         W_edge, b_edge, hidB, Q, 1);
    // iteration 2: hidB -> hidA
    k_agg<<<grid_n16, b256, 0, stream>>>(Q, edge_features, row_ptr, eids, senders, msgs);
    k_gru<<<grid_n16, b256, 0, stream>>>(hidB, msgs, Wi_gru, Wh_gru, bi_gru, bh_gru,
                                         W_edge, b_edge, hidA, Q, 1);
    // iteration 3: hidA -> hidB (no Q needed after)
    k_agg<<<grid_n16, b256, 0, stream>>>(Q, edge_features, row_ptr, eids, senders, msgs);
    k_gru<<<grid_n16, b256, 0, stream>>>(hidA, msgs, Wi_gru, Wh_gru, bi_gru, bh_gru,
                                         W_edge, b_edge, hidB, Q, 0);

    k_readout<<<grid_n, b256, 0, stream>>>(hidB, hidden0, W_ri, b_ri, W_rj, b_rj, out);
}

// Round 2
// 497.283 us; speedup vs baseline: 1.3320x; 1.3320x over previous
//
#include <hip/hip_runtime.h>

#define N_NODES 25000
#define N_EDGES 400000

// ---------------- fast transcendentals (fp32, ~2ulp) ----------------
__device__ __forceinline__ float fast_sigmoid(float x) {
    return __builtin_amdgcn_rcpf(1.0f + __expf(-x));
}
__device__ __forceinline__ float fast_tanh(float x) {
    return 1.0f - 2.0f * __builtin_amdgcn_rcpf(__expf(2.0f * x) + 1.0f);
}

// lane j receives value from lane j^k within its 32-lane half (k<16 keeps it
// inside the 16-lane node group). BitMode offset = (xor<<10)|(or<<5)|and.
#define SWZF(x, k) __int_as_float(__builtin_amdgcn_ds_swizzle(__float_as_int(x), ((k) << 10) | 0x1F))

// ---------------- K1: hidden0 = nf @ W_init + b_init ; copy; zero cnt --------
__global__ void __launch_bounds__(256) k_init(
        const float* __restrict__ nf, const float* __restrict__ Wini,
        const float* __restrict__ bini,
        float* __restrict__ hidden0, float* __restrict__ hid,
        int* __restrict__ cnt)
{
    int gtid = blockIdx.x * 256 + threadIdx.x;
    if (gtid <= N_NODES) cnt[gtid] = 0;
    int node = gtid >> 4;
    int j = gtid & 15;
    if (node >= N_NODES) return;

    const float4* nf4 = (const float4*)(nf + node * 32);
    float acc = bini[j];
#pragma unroll
    for (int g = 0; g < 8; ++g) {
        float4 v = nf4[g];
        acc = fmaf(v.x, Wini[(g*4+0)*16 + j], acc);
        acc = fmaf(v.y, Wini[(g*4+1)*16 + j], acc);
        acc = fmaf(v.z, Wini[(g*4+2)*16 + j], acc);
        acc = fmaf(v.w, Wini[(g*4+3)*16 + j], acc);
    }
    hidden0[node*16 + j] = acc;
    hid[node*16 + j] = acc;
}

// ---------------- sender-CSR build ----------------
__global__ void __launch_bounds__(256) k_hist(const int* __restrict__ send,
                                              int* __restrict__ cnt)
{
    int e = blockIdx.x * 256 + threadIdx.x;
    if (e < N_EDGES) atomicAdd(&cnt[send[e]], 1);
}

__global__ void __launch_bounds__(1024) k_scan(const int* __restrict__ cnt,
        int* __restrict__ row_ptr, int* __restrict__ cursor,
        float* __restrict__ out)
{
    __shared__ int sums[1024];
    int t = threadIdx.x;
    const int CH = (N_NODES + 1023) / 1024 + 1;   // 25 -> covers 25600
    int base = t * CH;
    int s = 0;
    for (int i = 0; i < CH; ++i) {
        int idx = base + i;
        if (idx < N_NODES) s += cnt[idx];
    }
    sums[t] = s;
    __syncthreads();
    for (int off = 1; off < 1024; off <<= 1) {
        int add = (t >= off) ? sums[t - off] : 0;
        __syncthreads();
        sums[t] += add;
        __syncthreads();
    }
    int run = sums[t] - s;
    for (int i = 0; i < CH; ++i) {
        int idx = base + i;
        if (idx < N_NODES) {
            row_ptr[idx] = run;
            cursor[idx]  = run;
            run += cnt[idx];
        }
    }
    if (t == 0) { row_ptr[N_NODES] = N_EDGES; out[0] = 0.0f; }
}

__global__ void __launch_bounds__(256) k_scatter(const int* __restrict__ send,
        const int* __restrict__ recv,
        int* __restrict__ cursor, int* __restrict__ eids,
        int* __restrict__ erecv)
{
    int e = blockIdx.x * 256 + threadIdx.x;
    if (e < N_EDGES) {
        int s = send[e];
        int pos = atomicAdd(&cursor[s], 1);
        eids[pos]  = e;
        erecv[pos] = recv[e];
    }
}

// efp[pos,:] = ef[eids[pos],:]  (edge features into sender-CSR order)
__global__ void __launch_bounds__(256) k_permute(const float* __restrict__ ef,
        const int* __restrict__ eids, float* __restrict__ efp)
{
    int gtid = blockIdx.x * 256 + threadIdx.x;
    int pos = gtid >> 4;
    int c = gtid & 15;
    if (pos < N_EDGES) efp[pos*16 + c] = ef[(size_t)eids[pos]*16 + c];
}

// ---------------- K3: sender-major message scatter ----------------
// group (16 lanes) = one sender s; lane = message dim m.
// q[f] = sum_h We[f, m*16+h] * h[s,h]  (We is 17KB -> L1-resident)
// per out-edge: msg = qb + sum_f efp[i,f]*q[f]; atomicAdd into msgs[recv,m].
__global__ void __launch_bounds__(256) k_agg(
        const float* __restrict__ hid, const float* __restrict__ efp,
        const float* __restrict__ We, const float* __restrict__ be,
        const int* __restrict__ row_ptr, const int* __restrict__ erecv,
        float* __restrict__ msgs)
{
    int gtid = blockIdx.x * 256 + threadIdx.x;
    int s = gtid >> 4;
    int m = gtid & 15;
    if (s >= N_NODES) return;

    float h[16];
    {
        const float4* h4 = (const float4*)(hid + s*16);
        float4 a = h4[0], b = h4[1], c = h4[2], d = h4[3];
        h[0]=a.x; h[1]=a.y; h[2]=a.z;  h[3]=a.w;
        h[4]=b.x; h[5]=b.y; h[6]=b.z;  h[7]=b.w;
        h[8]=c.x; h[9]=c.y; h[10]=c.z; h[11]=c.w;
        h[12]=d.x; h[13]=d.y; h[14]=d.z; h[15]=d.w;
    }
    float q[16];
#pragma unroll
    for (int f = 0; f < 16; ++f) {
        const float4* wf = (const float4*)(We + f*256 + m*16);
        float4 a = wf[0], b = wf[1], c = wf[2], d = wf[3];
        float acc;
        acc  = a.x*h[0]  + a.y*h[1]  + a.z*h[2]  + a.w*h[3];
        acc += b.x*h[4]  + b.y*h[5]  + b.z*h[6]  + b.w*h[7];
        acc += c.x*h[8]  + c.y*h[9]  + c.z*h[10] + c.w*h[11];
        acc += d.x*h[12] + d.y*h[13] + d.z*h[14] + d.w*h[15];
        q[f] = acc;
    }
    float qb;
    {
        const float4* bf = (const float4*)(be + m*16);
        float4 a = bf[0], b = bf[1], c = bf[2], d = bf[3];
        qb  = a.x*h[0]  + a.y*h[1]  + a.z*h[2]  + a.w*h[3];
        qb += b.x*h[4]  + b.y*h[5]  + b.z*h[6]  + b.w*h[7];
        qb += c.x*h[8]  + c.y*h[9]  + c.z*h[10] + c.w*h[11];
        qb += d.x*h[12] + d.y*h[13] + d.z*h[14] + d.w*h[15];
    }

    int beg = row_ptr[s];
    int end = row_ptr[s + 1];
    for (int i = beg; i < end; ++i) {
        int r = erecv[i];
        const float4* e4 = (const float4*)(efp + (size_t)i*16);
        float4 e0 = e4[0], e1 = e4[1], e2 = e4[2], e3 = e4[3];
        float a = qb;
        a = fmaf(e0.x, q[0],  a);
        a = fmaf(e0.y, q[1],  a);
        a = fmaf(e0.z, q[2],  a);
        a = fmaf(e0.w, q[3],  a);
        a = fmaf(e1.x, q[4],  a);
        a = fmaf(e1.y, q[5],  a);
        a = fmaf(e1.z, q[6],  a);
        a = fmaf(e1.w, q[7],  a);
        a = fmaf(e2.x, q[8],  a);
        a = fmaf(e2.y, q[9],  a);
        a = fmaf(e2.z, q[10], a);
        a = fmaf(e2.w, q[11], a);
        a = fmaf(e3.x, q[12], a);
        a = fmaf(e3.y, q[13], a);
        a = fmaf(e3.z, q[14], a);
        a = fmaf(e3.w, q[15], a);
        unsafeAtomicAdd(&msgs[r*16 + m], a);
    }
}

// ---------------- K4: GRU over seq=[hid||msgs] (T=32) ----------------
// 16 lanes per node, lane j = GRU unit j. h broadcast via ds_swizzle XOR
// (no LDS memory, no barrier): lane j holds h[j^k], weights pre-permuted.
__global__ void __launch_bounds__(256) k_gru(
        const float* __restrict__ hid_in, const float* __restrict__ msgs,
        const float* __restrict__ Wi, const float* __restrict__ Wh,
        const float* __restrict__ bi, const float* __restrict__ bh,
        float* __restrict__ hid_out)
{
    int gtid = blockIdx.x * 256 + threadIdx.x;
    int node = gtid >> 4;
    int j = gtid & 15;
    if (node >= N_NODES) return;

    float Wz[16], Wr[16], Wc[16];
#pragma unroll
    for (int k = 0; k < 16; ++k) {
        int l = j ^ k;
        Wz[k] = Wh[l*48 + j];
        Wr[k] = Wh[l*48 + 16 + j];
        Wc[k] = Wh[l*48 + 32 + j];
    }
    float Wiz = Wi[j], Wir = Wi[16+j], Wih = Wi[32+j];
    float cz   = bi[j] + bh[j];
    float cr   = bi[16+j] + bh[16+j];
    float bih_ = bi[32+j];
    float bhh_ = bh[32+j];

    float x[32];
    {
        const float4* a4 = (const float4*)(hid_in + node * 16);
        const float4* b4 = (const float4*)(msgs + node * 16);
#pragma unroll
        for (int g = 0; g < 4; ++g) {
            float4 v = a4[g];
            x[g*4+0]=v.x; x[g*4+1]=v.y; x[g*4+2]=v.z; x[g*4+3]=v.w;
        }
#pragma unroll
        for (int g = 0; g < 4; ++g) {
            float4 v = b4[g];
            x[16+g*4+0]=v.x; x[16+g*4+1]=v.y; x[16+g*4+2]=v.z; x[16+g*4+3]=v.w;
        }
    }

    float hn = 0.0f;

#define STEPK(k) { float v = SWZF(hn, k); \
        az = fmaf(v, Wz[k], az); ar = fmaf(v, Wr[k], ar); ac = fmaf(v, Wc[k], ac); }

#pragma unroll
    for (int t = 0; t < 32; ++t) {
        float xv = x[t];
        float az = fmaf(xv, Wiz, cz);
        float ar = fmaf(xv, Wir, cr);
        float ac = bhh_;
        az = fmaf(hn, Wz[0], az);
        ar = fmaf(hn, Wr[0], ar);
        ac = fmaf(hn, Wc[0], ac);
        STEPK(1)  STEPK(2)  STEPK(3)  STEPK(4)  STEPK(5)
        STEPK(6)  STEPK(7)  STEPK(8)  STEPK(9)  STEPK(10)
        STEPK(11) STEPK(12) STEPK(13) STEPK(14) STEPK(15)
        float z  = fast_sigmoid(az);
        float r  = fast_sigmoid(ar);
        float hc = fast_tanh(fmaf(xv, Wih, bih_) + r * ac);
        hn = fmaf(z, hn - hc, hc);   // z*h + (1-z)*hc
    }
#undef STEPK
    hid_out[node*16 + j] = hn;
}

// ---------------- K5: readout ----------------
__global__ void __launch_bounds__(256) k_readout(
        const float* __restrict__ hid, const float* __restrict__ hid0,
        const float* __restrict__ Wri, const float* __restrict__ bri,
        const float* __restrict__ Wrj, const float* __restrict__ brj,
        float* __restrict__ out)
{
    int n = blockIdx.x * 256 + threadIdx.x;
    float val = 0.0f;
    if (n < N_NODES) {
        const float4* h4 = (const float4*)(hid + n * 16);
        const float4* g4 = (const float4*)(hid0 + n * 16);
        float iv = bri[0];
        float jv = brj[0];
#pragma unroll
        for (int g = 0; g < 4; ++g) {
            float4 h  = h4[g];
            float4 h0 = g4[g];
            iv = fmaf(h.x,  Wri[g*4+0], iv);  iv = fmaf(h.y,  Wri[g*4+1], iv);
            iv = fmaf(h.z,  Wri[g*4+2], iv);  iv = fmaf(h.w,  Wri[g*4+3], iv);
            iv = fmaf(h0.x, Wri[16+g*4+0], iv); iv = fmaf(h0.y, Wri[16+g*4+1], iv);
            iv = fmaf(h0.z, Wri[16+g*4+2], iv); iv = fmaf(h0.w, Wri[16+g*4+3], iv);
            jv = fmaf(h.x,  Wrj[g*4+0], jv);  jv = fmaf(h.y,  Wrj[g*4+1], jv);
            jv = fmaf(h.z,  Wrj[g*4+2], jv);  jv = fmaf(h.w,  Wrj[g*4+3], jv);
        }
        val = iv * jv;
    }
#pragma unroll
    for (int off = 32; off > 0; off >>= 1)
        val += __shfl_xor(val, off, 64);
    __shared__ float wsum[4];
    int w = threadIdx.x >> 6;
    if ((threadIdx.x & 63) == 0) wsum[w] = val;
    __syncthreads();
    if (threadIdx.x == 0)
        atomicAdd(out, wsum[0] + wsum[1] + wsum[2] + wsum[3]);
}

// ---------------- launch ----------------
extern "C" void kernel_launch(void* const* d_in, const int* in_sizes, int n_in,
                              void* d_out, int out_size, void* d_ws, size_t ws_size,
                              hipStream_t stream)
{
    const float* node_features = (const float*)d_in[0];
    const float* edge_features = (const float*)d_in[1];
    const float* W_init = (const float*)d_in[2];
    const float* b_init = (const float*)d_in[3];
    const float* W_edge = (const float*)d_in[4];
    const float* b_edge = (const float*)d_in[5];
    const float* Wi_gru = (const float*)d_in[6];
    const float* Wh_gru = (const float*)d_in[7];
    const float* bi_gru = (const float*)d_in[8];
    const float* bh_gru = (const float*)d_in[9];
    const float* W_ri = (const float*)d_in[10];
    const float* b_ri = (const float*)d_in[11];
    const float* W_rj = (const float*)d_in[12];
    const float* b_rj = (const float*)d_in[13];
    const int* receivers = (const int*)d_in[14];
    const int* senders   = (const int*)d_in[15];
    float* out = (float*)d_out;

    // workspace carve: floats then ints; ~35.5 MB
    float* fb      = (float*)d_ws;
    float* hidden0 = fb;                 // 400000
    float* hidA    = fb + 400000;        // 400000
    float* hidB    = fb + 800000;        // 400000
    float* msgs    = fb + 1200000;       // 400000
    float* efp     = fb + 1600000;       // 6400000 (E*16)
    int* ib      = (int*)(fb + 8000000);
    int* cnt     = ib;                   // 25024
    int* row_ptr = ib + 25024;           // 25024
    int* cursor  = ib + 50048;           // 25024
    int* eids    = ib + 75072;           // 400000
    int* erecv   = ib + 475072;          // 400000

    dim3 b256(256);
    int grid_n16 = (N_NODES * 16 + 255) / 256;   // 1563
    int grid_e   = (N_EDGES + 255) / 256;        // 1563
    int grid_e16 = (N_EDGES * 16 + 255) / 256;   // 25000
    int grid_n   = (N_NODES + 255) / 256;        // 98

    k_init<<<grid_n16, b256, 0, stream>>>(node_features, W_init, b_init,
                                          hidden0, hidA, cnt);
    k_hist<<<grid_e, b256, 0, stream>>>(senders, cnt);
    k_scan<<<1, 1024, 0, stream>>>(cnt, row_ptr, cursor, out);
    k_scatter<<<grid_e, b256, 0, stream>>>(senders, receivers, cursor, eids, erecv);
    k_permute<<<grid_e16, b256, 0, stream>>>(edge_features, eids, efp);

    float* hin = hidA;
    float* hout = hidB;
    for (int it = 0; it < 3; ++it) {
        hipMemsetAsync(msgs, 0, N_NODES * 16 * sizeof(float), stream);
        k_agg<<<grid_n16, b256, 0, stream>>>(hin, efp, W_edge, b_edge,
                                             row_ptr, erecv, msgs);
        k_gru<<<grid_n16, b256, 0, stream>>>(hin, msgs, Wi_gru, Wh_gru,
                                             bi_gru, bh_gru, hout);
        float* t = hin; hin = hout; hout = t;
    }

    k_readout<<<grid_n, b256, 0, stream>>>(hin, hidden0, W_ri, b_ri, W_rj, b_rj, out);
}